// Round 2
// baseline (265.951 us; speedup 1.0000x reference)
//
#include <hip/hip_runtime.h>
#include <hip/hip_bf16.h>

#define BATCH 128
#define WIDTH 8192
#define DIM   64
#define FILT  32
#define KSZ   3
#define WOUT  8190
#define WT    254      // output rows per block
#define NBX   33       // ceil(8190/254)
#define XROWS 258      // 256 staged + 2 zero-pad (halo reads for masked rows)

typedef __attribute__((ext_vector_type(8))) _Float16 f16x8;
typedef __attribute__((ext_vector_type(4))) _Float16 f16x4;
typedef __attribute__((ext_vector_type(4))) float f32x4;

// monotonic float <-> uint mapping for atomic min/max
__device__ inline unsigned encf(float f) {
  unsigned u = __float_as_uint(f);
  return (u & 0x80000000u) ? ~u : (u | 0x80000000u);
}
__device__ inline float decf(unsigned u) {
  unsigned b = (u & 0x80000000u) ? (u & 0x7fffffffu) : ~u;
  return __uint_as_float(b);
}

__global__ void init_mm(unsigned* mm) {
  int t = threadIdx.x;
  if (t < BATCH) { mm[2*t] = 0u; mm[2*t+1] = 0xFFFFFFFFu; }
}

// PASS 0: conv -> per-sample min/max (atomics into mm). PASS 1: conv -> normalize -> out.
template<int PASS>
__global__ __launch_bounds__(256)
void conv_pass(const float* __restrict__ x, const float* __restrict__ ker,
               float* __restrict__ out, unsigned* __restrict__ mm)
{
  __shared__ __align__(16) short xs[XROWS*DIM];     // [row][d] f16, swizzled
  __shared__ __align__(16) short ks[KSZ*FILT*DIM];  // [k][f][d] f16, swizzled

  const int t  = threadIdx.x;
  const int l  = t & 63;
  const int wv = t >> 6;
  const int b  = blockIdx.y;
  const int w0 = blockIdx.x * WT;

  // ---- stage weights: fp32 [k][d][f] -> f16 LDS [k][f][d], XOR-swizzled
  #pragma unroll
  for (int i = 0; i < 24; ++i) {
    int idx = t + i*256;                 // 6144 elements total
    int k = idx >> 11, rem = idx & 2047;
    int d = rem >> 5,  f = rem & 31;
    _Float16 hv = (_Float16)ker[idx];
    int byte = ((k*FILT + f)*DIM + d)*2;
    byte ^= (f & 7) << 4;
    ks[byte >> 1] = __builtin_bit_cast(short, hv);
  }

  // ---- stage x rows [w0, w0+256) -> f16 LDS, XOR-swizzled
  const float* xb = x + ((long)b*WIDTH + w0)*DIM;
  #pragma unroll
  for (int i = 0; i < 16; ++i) {
    int idx4 = i*256 + t;                // over [256 rows][16 float4]
    int row = idx4 >> 4;
    int d0  = (idx4 & 15) * 4;
    f32x4 v = {0.f, 0.f, 0.f, 0.f};
    if (w0 + row < WIDTH)
      v = *reinterpret_cast<const f32x4*>(xb + row*DIM + d0);
    f16x4 hv;
    hv.x = (_Float16)v.x; hv.y = (_Float16)v.y;
    hv.z = (_Float16)v.z; hv.w = (_Float16)v.w;
    int byte = row*128 + d0*2;
    byte ^= (row & 7) << 4;
    *reinterpret_cast<f16x4*>(&xs[byte >> 1]) = hv;
  }
  if (t < 32) {                          // zero halo rows 256,257
    int row = 256 + (t >> 4);
    int d0  = (t & 15) * 4;
    int byte = row*128 + d0*2;
    byte ^= (row & 7) << 4;
    f16x4 z = {(_Float16)0.f, (_Float16)0.f, (_Float16)0.f, (_Float16)0.f};
    *reinterpret_cast<f16x4*>(&xs[byte >> 1]) = z;
  }
  __syncthreads();

  // ---- B fragments (shared across all M): 12 frags x 4 VGPR
  f16x8 Bf[KSZ][2][2];
  #pragma unroll
  for (int s = 0; s < KSZ; ++s)
    #pragma unroll
    for (int kh = 0; kh < 2; ++kh)
      #pragma unroll
      for (int nt = 0; nt < 2; ++nt) {
        int f  = nt*16 + (l & 15);
        int d0 = kh*32 + (l >> 4)*8;
        int byte = ((s*FILT + f)*DIM + d0)*2;
        byte ^= (f & 7) << 4;
        Bf[s][kh][nt] = *reinterpret_cast<const f16x8*>(&ks[byte >> 1]);
      }

  f32x4 acc[4][2];
  #pragma unroll
  for (int mt = 0; mt < 4; ++mt)
    #pragma unroll
    for (int nt = 0; nt < 2; ++nt)
      acc[mt][nt] = (f32x4){0.f, 0.f, 0.f, 0.f};

  // ---- main loop: 3 shifts x 2 K-halves; wave owns rows [wv*64, wv*64+64)
  #pragma unroll
  for (int s = 0; s < KSZ; ++s) {
    #pragma unroll
    for (int kh = 0; kh < 2; ++kh) {
      f16x8 a[4];
      #pragma unroll
      for (int mt = 0; mt < 4; ++mt) {
        int row = wv*64 + mt*16 + (l & 15) + s;
        int d0  = kh*32 + (l >> 4)*8;
        int byte = row*128 + d0*2;
        byte ^= (row & 7) << 4;
        a[mt] = *reinterpret_cast<const f16x8*>(&xs[byte >> 1]);
      }
      #pragma unroll
      for (int mt = 0; mt < 4; ++mt)
        #pragma unroll
        for (int nt = 0; nt < 2; ++nt)
          acc[mt][nt] = __builtin_amdgcn_mfma_f32_16x16x32_f16(
              a[mt], Bf[s][kh][nt], acc[mt][nt], 0, 0, 0);
    }
  }

  if (PASS == 0) {
    float mx = -INFINITY, mn = INFINITY;
    #pragma unroll
    for (int mt = 0; mt < 4; ++mt)
      #pragma unroll
      for (int nt = 0; nt < 2; ++nt)
        #pragma unroll
        for (int r = 0; r < 4; ++r) {
          int wl = wv*64 + mt*16 + (l >> 4)*4 + r;   // C-row = (lane>>4)*4+reg
          if (wl < WT && w0 + wl < WOUT) {
            float v = acc[mt][nt][r];
            mx = fmaxf(mx, v); mn = fminf(mn, v);
          }
        }
    #pragma unroll
    for (int off = 32; off > 0; off >>= 1) {
      mx = fmaxf(mx, __shfl_down(mx, off));
      mn = fminf(mn, __shfl_down(mn, off));
    }
    if (l == 0) {
      atomicMax(&mm[2*b],   encf(mx));
      atomicMin(&mm[2*b+1], encf(mn));
    }
  } else {
    float mxv = decf(mm[2*b]);
    float mnv = decf(mm[2*b+1]);
    float rs = 1.0f / (mxv - mnv);
    #pragma unroll
    for (int mt = 0; mt < 4; ++mt)
      #pragma unroll
      for (int nt = 0; nt < 2; ++nt)
        #pragma unroll
        for (int r = 0; r < 4; ++r) {
          int wl = wv*64 + mt*16 + (l >> 4)*4 + r;
          if (wl < WT && w0 + wl < WOUT) {
            int f = nt*16 + (l & 15);
            out[((long)b*WOUT + (w0 + wl))*FILT + f] = (acc[mt][nt][r] - mnv)*rs;
          }
        }
  }
}

extern "C" void kernel_launch(void* const* d_in, const int* in_sizes, int n_in,
                              void* d_out, int out_size, void* d_ws, size_t ws_size,
                              hipStream_t stream) {
  const float* x   = (const float*)d_in[0];
  const float* ker = (const float*)d_in[1];
  float* out = (float*)d_out;
  unsigned* mm = (unsigned*)d_ws;        // 128 samples x {max,min} encoded uints (1 KB)

  init_mm<<<dim3(1), dim3(256), 0, stream>>>(mm);
  dim3 grid(NBX, BATCH);
  conv_pass<0><<<grid, dim3(256), 0, stream>>>(x, ker, nullptr, mm);
  conv_pass<1><<<grid, dim3(256), 0, stream>>>(x, ker, out, mm);
}